// Round 7
// baseline (363.775 us; speedup 1.0000x reference)
//
#include <hip/hip_runtime.h>

#define CDIM 64
#define KCODES 1024
#define ZQ_ELEMS (32 * 64 * 64 * 64)  // 8388608
#define NROWS 131072
#define FLT_BIG 3.402823466e38f
#define NBLK 2048                     // 131072 rows / 64 rows per block
#define ZSTRIDE 68                    // 64 floats + 4 pad -> conflict-min ds_read_b128

// numpy-exact semantics: A,B = 8-acc pairwise sum of squares over 64 elems;
// M = strictly sequential fma over c (sgemm microkernel order);
// d = fl(fl(A+B) - 2M); argmin strict < ascending k (first index wins).
// Block = 64 rows x 4 k-segments (wave w scans codes [w*256, w*256+256)).
// z rows live in LDS (cheap reloads); codebook on the scalar s_load path.

__device__ __forceinline__ float pairwise_sq64(const float* v) {
    float r[8];
    #pragma unroll
    for (int j = 0; j < 8; ++j) r[j] = __fmul_rn(v[j], v[j]);
    #pragma unroll
    for (int m = 1; m < 8; ++m) {
        #pragma unroll
        for (int j = 0; j < 8; ++j)
            r[j] = __fadd_rn(r[j], __fmul_rn(v[8 * m + j], v[8 * m + j]));
    }
    return __fadd_rn(__fadd_rn(__fadd_rn(r[0], r[1]), __fadd_rn(r[2], r[3])),
                     __fadd_rn(__fadd_rn(r[4], r[5]), __fadd_rn(r[6], r[7])));
}

// 8 codes x 4 dims = 32 FMAs; z float4 comes from LDS (one ds_read_b128).
#define KSTEP8(q) \
    { \
        float4 zq = zr4[q]; \
        float4 e0 = C0[q], e1 = C1[q], e2 = C2[q], e3 = C3[q]; \
        float4 e4 = C4[q], e5 = C5[q], e6 = C6[q], e7 = C7[q]; \
        m0 = __fmaf_rn(zq.x, e0.x, m0); m0 = __fmaf_rn(zq.y, e0.y, m0); \
        m0 = __fmaf_rn(zq.z, e0.z, m0); m0 = __fmaf_rn(zq.w, e0.w, m0); \
        m1 = __fmaf_rn(zq.x, e1.x, m1); m1 = __fmaf_rn(zq.y, e1.y, m1); \
        m1 = __fmaf_rn(zq.z, e1.z, m1); m1 = __fmaf_rn(zq.w, e1.w, m1); \
        m2 = __fmaf_rn(zq.x, e2.x, m2); m2 = __fmaf_rn(zq.y, e2.y, m2); \
        m2 = __fmaf_rn(zq.z, e2.z, m2); m2 = __fmaf_rn(zq.w, e2.w, m2); \
        m3 = __fmaf_rn(zq.x, e3.x, m3); m3 = __fmaf_rn(zq.y, e3.y, m3); \
        m3 = __fmaf_rn(zq.z, e3.z, m3); m3 = __fmaf_rn(zq.w, e3.w, m3); \
        m4 = __fmaf_rn(zq.x, e4.x, m4); m4 = __fmaf_rn(zq.y, e4.y, m4); \
        m4 = __fmaf_rn(zq.z, e4.z, m4); m4 = __fmaf_rn(zq.w, e4.w, m4); \
        m5 = __fmaf_rn(zq.x, e5.x, m5); m5 = __fmaf_rn(zq.y, e5.y, m5); \
        m5 = __fmaf_rn(zq.z, e5.z, m5); m5 = __fmaf_rn(zq.w, e5.w, m5); \
        m6 = __fmaf_rn(zq.x, e6.x, m6); m6 = __fmaf_rn(zq.y, e6.y, m6); \
        m6 = __fmaf_rn(zq.z, e6.z, m6); m6 = __fmaf_rn(zq.w, e6.w, m6); \
        m7 = __fmaf_rn(zq.x, e7.x, m7); m7 = __fmaf_rn(zq.y, e7.y, m7); \
        m7 = __fmaf_rn(zq.z, e7.z, m7); m7 = __fmaf_rn(zq.w, e7.w, m7); \
    }

#define DBEST(j, mj, Bj) \
    { \
        float dd = __fsub_rn(__fadd_rn(A, Bj), __fadd_rn(mj, mj)); \
        if (dd < best) { best = dd; bi = k + j; } \
    }

#define LSTEP(i) \
    { \
        float4 qv = cq4[i]; \
        float4 zi = zr4[i]; \
        zo[(4 * i + 0) << 12] = qv.x; \
        zo[(4 * i + 1) << 12] = qv.y; \
        zo[(4 * i + 2) << 12] = qv.z; \
        zo[(4 * i + 3) << 12] = qv.w; \
        lsum = fmaf(qv.x - zi.x, qv.x - zi.x, lsum); \
        lsum = fmaf(qv.y - zi.y, qv.y - zi.y, lsum); \
        lsum = fmaf(qv.z - zi.z, qv.z - zi.z, lsum); \
        lsum = fmaf(qv.w - zi.w, qv.w - zi.w, lsum); \
    }

__global__ __launch_bounds__(256, 2) void vq_main(const float* __restrict__ z,
                                                  const float* __restrict__ cb,
                                                  float* __restrict__ zq_out,
                                                  float* __restrict__ idx_out,
                                                  double* __restrict__ part) {
    __shared__ float sZ[64 * ZSTRIDE];   // 17.4 KB, padded rows
    __shared__ float sB[KCODES];         // 4 KB code norms
    __shared__ float sD[256];
    __shared__ int sI[256];
    const int tid = threadIdx.x;
    const int lane = tid & 63;           // row within block
    const int kseg = tid >> 6;           // wave -> k segment

    const int n0 = blockIdx.x * 64;
    const int b = n0 >> 12;
    const int hw0 = n0 & 4095;
    const float* __restrict__ zb = z + ((size_t)b << 18) + hw0;

    // stage z: thread (lane, kseg) loads 16 c-planes, coalesced across lanes
    #pragma unroll
    for (int it = 0; it < 16; ++it) {
        int c = kseg * 16 + it;
        sZ[lane * ZSTRIDE + c] = zb[((size_t)c << 12) + lane];
    }

    // B_k, numpy 8-acc pairwise (4 codes per thread, one-time)
    for (int k = tid; k < KCODES; k += 256) {
        sB[k] = pairwise_sq64(cb + k * CDIM);
    }
    __syncthreads();

    const float4* __restrict__ zr4 = (const float4*)(sZ + lane * ZSTRIDE);

    // A, numpy pairwise, from LDS row
    float zarr[CDIM];
    #pragma unroll
    for (int q = 0; q < 16; ++q) {
        float4 v = zr4[q];
        zarr[4 * q + 0] = v.x; zarr[4 * q + 1] = v.y;
        zarr[4 * q + 2] = v.z; zarr[4 * q + 3] = v.w;
    }
    const float A = pairwise_sq64(zarr);

    float best = FLT_BIG;
    int bi = 0;
    // SGPR segment base -> provably uniform codebook addresses -> s_load path
    const int kbase = __builtin_amdgcn_readfirstlane(kseg << 8);

    for (int k = kbase; k < kbase + 256; k += 8) {
        const float4* __restrict__ C0 = (const float4*)(cb + (size_t)(k + 0) * CDIM);
        const float4* __restrict__ C1 = (const float4*)(cb + (size_t)(k + 1) * CDIM);
        const float4* __restrict__ C2 = (const float4*)(cb + (size_t)(k + 2) * CDIM);
        const float4* __restrict__ C3 = (const float4*)(cb + (size_t)(k + 3) * CDIM);
        const float4* __restrict__ C4 = (const float4*)(cb + (size_t)(k + 4) * CDIM);
        const float4* __restrict__ C5 = (const float4*)(cb + (size_t)(k + 5) * CDIM);
        const float4* __restrict__ C6 = (const float4*)(cb + (size_t)(k + 6) * CDIM);
        const float4* __restrict__ C7 = (const float4*)(cb + (size_t)(k + 7) * CDIM);
        float m0 = 0.f, m1 = 0.f, m2 = 0.f, m3 = 0.f;
        float m4 = 0.f, m5 = 0.f, m6 = 0.f, m7 = 0.f;
        KSTEP8(0)  KSTEP8(1)  KSTEP8(2)  KSTEP8(3)
        KSTEP8(4)  KSTEP8(5)  KSTEP8(6)  KSTEP8(7)
        KSTEP8(8)  KSTEP8(9)  KSTEP8(10) KSTEP8(11)
        KSTEP8(12) KSTEP8(13) KSTEP8(14) KSTEP8(15)

        float4 Ba = ((const float4*)sB)[(k >> 2) + 0];
        float4 Bb = ((const float4*)sB)[(k >> 2) + 1];
        DBEST(0, m0, Ba.x) DBEST(1, m1, Ba.y) DBEST(2, m2, Ba.z) DBEST(3, m3, Ba.w)
        DBEST(4, m4, Bb.x) DBEST(5, m5, Bb.y) DBEST(6, m6, Bb.z) DBEST(7, m7, Bb.w)
    }

    sD[tid] = best;
    sI[tid] = bi;
    __syncthreads();

    if (tid < 64) {
        // combine segments in ascending-k order; strict < keeps first index
        float bd = sD[tid];
        int bk = sI[tid];
        #pragma unroll
        for (int s = 1; s < 4; ++s) {
            float d = sD[s * 64 + tid];
            int kk = sI[s * 64 + tid];
            if (d < bd) { bd = d; bk = kk; }
        }

        const int n = n0 + tid;
        idx_out[n] = (float)bk;

        const float4* __restrict__ cq4 = (const float4*)(cb + (size_t)bk * CDIM);
        float* __restrict__ zo = zq_out + ((size_t)b << 18) + (n & 4095);
        float lsum = 0.f;
        LSTEP(0)  LSTEP(1)  LSTEP(2)  LSTEP(3)
        LSTEP(4)  LSTEP(5)  LSTEP(6)  LSTEP(7)
        LSTEP(8)  LSTEP(9)  LSTEP(10) LSTEP(11)
        LSTEP(12) LSTEP(13) LSTEP(14) LSTEP(15)

        double ls = (double)lsum;
        for (int off = 32; off > 0; off >>= 1) ls += __shfl_down(ls, off, 64);
        if (tid == 0) part[blockIdx.x] = ls;
    }
}

__global__ void vq_finalize(const double* __restrict__ part, float* __restrict__ loss_out) {
    __shared__ double s[16];
    const int tid = threadIdx.x;       // 1024 threads, one block
    double v = part[tid] + part[tid + 1024];
    for (int off = 32; off > 0; off >>= 1) v += __shfl_down(v, off, 64);
    if ((tid & 63) == 0) s[tid >> 6] = v;
    __syncthreads();
    if (tid == 0) {
        double t = 0.0;
        #pragma unroll
        for (int i = 0; i < 16; ++i) t += s[i];
        // loss = codebook_loss + 0.25*commitment = 1.25 * mean((z_q - z)^2)
        *loss_out = (float)(1.25 * t / (double)ZQ_ELEMS);
    }
}

extern "C" void kernel_launch(void* const* d_in, const int* in_sizes, int n_in,
                              void* d_out, int out_size, void* d_ws, size_t ws_size,
                              hipStream_t stream) {
    const float* z  = (const float*)d_in[0];
    const float* cb = (const float*)d_in[1];
    float* out  = (float*)d_out;
    float* zq   = out;                       // 8388608
    float* loss = out + ZQ_ELEMS;            // 1
    float* idx  = out + ZQ_ELEMS + 1;        // 131072
    double* part = (double*)d_ws;            // 2048 doubles (16 KB)

    vq_main<<<NBLK, 256, 0, stream>>>(z, cb, zq, idx, part);
    vq_finalize<<<1, 1024, 0, stream>>>(part, loss);
}

// Round 8
// 200.451 us; speedup vs baseline: 1.8148x; 1.8148x over previous
//
#include <hip/hip_runtime.h>

#define CDIM 64
#define KCODES 1024
#define ZQ_ELEMS (32 * 64 * 64 * 64)  // 8388608
#define NROWS 131072
#define FLT_BIG 3.402823466e38f
#define RPB 128                       // rows per block
#define NBLK (NROWS / RPB)            // 1024
#define DELTA 1e-4f                   // screening slack (see analysis)
#define ZLS 72                        // LDS bf16 row stride (16B-aligned rows)
#define CSLOTS 48                     // 16 lanes x top-3 per row

// ws layout: [0,8KB) part | [16KB,20KB) Bsq | [32KB,+128KB) e1 | [+128KB,+128KB) e2
#define WS_BSQ_OFF 16384
#define WS_E1_OFF  32768
#define WS_E2_OFF  (32768 + 131072)
#define WS_NEEDED  (WS_E2_OFF + 131072)

typedef __bf16 bf16x8 __attribute__((ext_vector_type(8)));
typedef float  f32x4  __attribute__((ext_vector_type(4)));

// numpy-exact pairwise sum of squares (8 accumulators, numpy pairwise order)
__device__ __forceinline__ float pairwise_sq64(const float* v) {
    float r[8];
    #pragma unroll
    for (int j = 0; j < 8; ++j) r[j] = __fmul_rn(v[j], v[j]);
    #pragma unroll
    for (int m = 1; m < 8; ++m) {
        #pragma unroll
        for (int j = 0; j < 8; ++j)
            r[j] = __fadd_rn(r[j], __fmul_rn(v[8 * m + j], v[8 * m + j]));
    }
    return __fadd_rn(__fadd_rn(__fadd_rn(r[0], r[1]), __fadd_rn(r[2], r[3])),
                     __fadd_rn(__fadd_rn(r[4], r[5]), __fadd_rn(r[6], r[7])));
}

// ---------------- prep: exact code norms + bf16-split codebook in B-fragment layout ----
// B-frag (16x16x32): lane l supplies code n = tile*16 + (l&15), k-elems 8*(l>>4)+i (+32*kstep).
// Stored so a wave's fragment load is one contiguous 1KB dwordx4 burst:
//   frag[(tile*2+ks)*64 + lane] = 8 bf16.
__global__ __launch_bounds__(256) void vq_prep(const float* __restrict__ cb,
                                               float* __restrict__ Bsq,
                                               __bf16* __restrict__ e1,
                                               __bf16* __restrict__ e2) {
    const int k = blockIdx.x * 256 + threadIdx.x;   // 4 blocks -> 1024 codes
    const float* __restrict__ ck = cb + k * CDIM;
    float v[CDIM];
    #pragma unroll
    for (int q = 0; q < 16; ++q) {
        float4 t = ((const float4*)ck)[q];
        v[4 * q + 0] = t.x; v[4 * q + 1] = t.y; v[4 * q + 2] = t.z; v[4 * q + 3] = t.w;
    }
    Bsq[k] = pairwise_sq64(v);

    __bf16 h[CDIM], l[CDIM];
    #pragma unroll
    for (int c = 0; c < CDIM; ++c) {
        h[c] = (__bf16)v[c];
        l[c] = (__bf16)(v[c] - (float)h[c]);
    }
    const int t = k >> 4, kin = k & 15;
    bf16x8* F1 = (bf16x8*)e1;
    bf16x8* F2 = (bf16x8*)e2;
    #pragma unroll
    for (int ks = 0; ks < 2; ++ks) {
        #pragma unroll
        for (int g = 0; g < 4; ++g) {
            bf16x8 a, b;
            #pragma unroll
            for (int i = 0; i < 8; ++i) {
                a[i] = h[ks * 32 + 8 * g + i];
                b[i] = l[ks * 32 + 8 * g + i];
            }
            const int off = (t * 2 + ks) * 64 + ((g << 4) | kin);
            F1[off] = a;
            F2[off] = b;
        }
    }
}

// ---------------- main: MFMA screen + exact rescue ----------------
__global__ __launch_bounds__(256, 2) void vq_main(const float* __restrict__ z,
                                                  const float* __restrict__ cb,
                                                  const float* __restrict__ Bsq,
                                                  const __bf16* __restrict__ e1,
                                                  const __bf16* __restrict__ e2,
                                                  float* __restrict__ zq_out,
                                                  float* __restrict__ idx_out,
                                                  double* __restrict__ part) {
    __shared__ __bf16 sZh[RPB * ZLS];       // 18.4 KB z-hi
    __shared__ __bf16 sZl[RPB * ZLS];       // 18.4 KB z-lo
    __shared__ float  sB[KCODES];           // 4 KB exact code norms
    __shared__ float  sA[RPB];              // exact row norms
    __shared__ float  sCval[RPB * CSLOTS];  // 24.6 KB candidate t~
    __shared__ short  sCk[RPB * CSLOTS];    // 12.3 KB candidate k
    __shared__ double sP2[2];

    const int tid = threadIdx.x;
    const int n0 = blockIdx.x * RPB;
    const int b = n0 >> 12;
    const int hw0 = n0 & 4095;

    for (int k = tid; k < KCODES; k += 256) sB[k] = Bsq[k];

    // ---- phase 0: stage z (rows 0..127), exact A, bf16 hi/lo split ----
    if (tid < RPB) {
        const float* __restrict__ zp = z + ((size_t)b << 18) + hw0 + tid;
        float zv[CDIM];
        #pragma unroll
        for (int c = 0; c < CDIM; ++c) zv[c] = zp[(size_t)c << 12];  // coalesced across threads
        sA[tid] = pairwise_sq64(zv);
        #pragma unroll
        for (int c = 0; c < CDIM; ++c) {
            __bf16 h = (__bf16)zv[c];
            sZh[tid * ZLS + c] = h;
            sZl[tid * ZLS + c] = (__bf16)(zv[c] - (float)h);
        }
    }
    __syncthreads();

    // ---- phase 1: MFMA screen. wave w owns rows [32w, 32w+32) x all 1024 codes ----
    const int lane = tid & 63, w = tid >> 6;
    const int g = lane >> 4, li = lane & 15;
    const int rowA = 32 * w + li;        // row-tile set 0
    const int rowB = rowA + 16;          // row-tile set 1
    const int co = 8 * g;

    const bf16x8 zh00 = *(const bf16x8*)(sZh + rowA * ZLS + co);
    const bf16x8 zh01 = *(const bf16x8*)(sZh + rowA * ZLS + co + 32);
    const bf16x8 zh10 = *(const bf16x8*)(sZh + rowB * ZLS + co);
    const bf16x8 zh11 = *(const bf16x8*)(sZh + rowB * ZLS + co + 32);
    const bf16x8 zl00 = *(const bf16x8*)(sZl + rowA * ZLS + co);
    const bf16x8 zl01 = *(const bf16x8*)(sZl + rowA * ZLS + co + 32);
    const bf16x8 zl10 = *(const bf16x8*)(sZl + rowB * ZLS + co);
    const bf16x8 zl11 = *(const bf16x8*)(sZl + rowB * ZLS + co + 32);

    const bf16x8* __restrict__ F1 = (const bf16x8*)e1;
    const bf16x8* __restrict__ F2 = (const bf16x8*)e2;

    float tv[2][4][3];
    int   tk[2][4][3];
    #pragma unroll
    for (int s = 0; s < 2; ++s)
        #pragma unroll
        for (int j = 0; j < 4; ++j)
            #pragma unroll
            for (int q = 0; q < 3; ++q) { tv[s][j][q] = FLT_BIG; tk[s][j][q] = 0; }

    const f32x4 zero = {0.f, 0.f, 0.f, 0.f};

    for (int t = 0; t < 64; ++t) {
        const bf16x8 e1a = F1[(2 * t) * 64 + lane];
        const bf16x8 e1b = F1[(2 * t + 1) * 64 + lane];
        const bf16x8 e2a = F2[(2 * t) * 64 + lane];
        const bf16x8 e2b = F2[(2 * t + 1) * 64 + lane];
        const float Bval = sB[t * 16 + li];
        const int code = t * 16 + li;

        // set 0: acc split into 2 chains for ILP
        f32x4 aA0 = __builtin_amdgcn_mfma_f32_16x16x32_bf16(zh00, e1a, zero, 0, 0, 0);
        aA0       = __builtin_amdgcn_mfma_f32_16x16x32_bf16(zh01, e1b, aA0, 0, 0, 0);
        f32x4 aB0 = __builtin_amdgcn_mfma_f32_16x16x32_bf16(zh00, e2a, zero, 0, 0, 0);
        aB0       = __builtin_amdgcn_mfma_f32_16x16x32_bf16(zh01, e2b, aB0, 0, 0, 0);
        aB0       = __builtin_amdgcn_mfma_f32_16x16x32_bf16(zl00, e1a, aB0, 0, 0, 0);
        aB0       = __builtin_amdgcn_mfma_f32_16x16x32_bf16(zl01, e1b, aB0, 0, 0, 0);
        // set 1
        f32x4 aA1 = __builtin_amdgcn_mfma_f32_16x16x32_bf16(zh10, e1a, zero, 0, 0, 0);
        aA1       = __builtin_amdgcn_mfma_f32_16x16x32_bf16(zh11, e1b, aA1, 0, 0, 0);
        f32x4 aB1 = __builtin_amdgcn_mfma_f32_16x16x32_bf16(zh10, e2a, zero, 0, 0, 0);
        aB1       = __builtin_amdgcn_mfma_f32_16x16x32_bf16(zh11, e2b, aB1, 0, 0, 0);
        aB1       = __builtin_amdgcn_mfma_f32_16x16x32_bf16(zl10, e1a, aB1, 0, 0, 0);
        aB1       = __builtin_amdgcn_mfma_f32_16x16x32_bf16(zl11, e1b, aB1, 0, 0, 0);

        #pragma unroll
        for (int s = 0; s < 2; ++s) {
            #pragma unroll
            for (int j = 0; j < 4; ++j) {
                const float acc = (s == 0) ? (aA0[j] + aB0[j]) : (aA1[j] + aB1[j]);
                const float v = Bval - 2.0f * acc;   // t~ (screen only; slack in DELTA)
                if (v < tv[s][j][0]) {
                    tv[s][j][2] = tv[s][j][1]; tk[s][j][2] = tk[s][j][1];
                    tv[s][j][1] = tv[s][j][0]; tk[s][j][1] = tk[s][j][0];
                    tv[s][j][0] = v;           tk[s][j][0] = code;
                } else if (v < tv[s][j][1]) {
                    tv[s][j][2] = tv[s][j][1]; tk[s][j][2] = tk[s][j][1];
                    tv[s][j][1] = v;           tk[s][j][1] = code;
                } else if (v < tv[s][j][2]) {
                    tv[s][j][2] = v;           tk[s][j][2] = code;
                }
            }
        }
    }

    // write per-lane top-3 candidates (D layout: col=lane&15, row=4*(lane>>4)+j  [verified])
    #pragma unroll
    for (int s = 0; s < 2; ++s) {
        #pragma unroll
        for (int j = 0; j < 4; ++j) {
            const int row = 32 * w + 16 * s + 4 * g + j;
            const int base = row * CSLOTS + li * 3;
            #pragma unroll
            for (int q = 0; q < 3; ++q) {
                sCval[base + q] = tv[s][j][q];
                sCk[base + q] = (short)tk[s][j][q];
            }
        }
    }
    __syncthreads();

    // ---- phase 2: exact numpy-semantics rescue, one thread per row ----
    if (tid < RPB) {
        const int r = tid;
        const int n = n0 + r;

        float gmin = FLT_BIG;
        #pragma unroll 8
        for (int s = 0; s < CSLOTS; ++s) gmin = fminf(gmin, sCval[r * CSLOTS + s]);
        const float thr = gmin + DELTA;

        const float* __restrict__ zp = z + ((size_t)b << 18) + hw0 + r;
        float zrow[CDIM];
        #pragma unroll
        for (int c = 0; c < CDIM; ++c) zrow[c] = zp[(size_t)c << 12];
        const float A = sA[r];

        float bd = FLT_BIG;
        int bk = 1 << 30;
        for (int s = 0; s < CSLOTS; ++s) {
            const float v = sCval[r * CSLOTS + s];
            if (v <= thr) {
                const int k = (int)sCk[r * CSLOTS + s];
                const float4* __restrict__ ek = (const float4*)(cb + (size_t)k * CDIM);
                float m = 0.f;
                #pragma unroll
                for (int q = 0; q < 16; ++q) {      // BLAS order: sequential in c
                    float4 e = ek[q];
                    m = __fmaf_rn(zrow[4 * q + 0], e.x, m);
                    m = __fmaf_rn(zrow[4 * q + 1], e.y, m);
                    m = __fmaf_rn(zrow[4 * q + 2], e.z, m);
                    m = __fmaf_rn(zrow[4 * q + 3], e.w, m);
                }
                const float d = __fsub_rn(__fadd_rn(A, sB[k]), __fadd_rn(m, m));
                if (d < bd || (d == bd && k < bk)) { bd = d; bk = k; }
            }
        }

        idx_out[n] = (float)bk;

        const float4* __restrict__ cq = (const float4*)(cb + (size_t)bk * CDIM);
        float* __restrict__ zo = zq_out + ((size_t)b << 18) + hw0 + r;
        float lsum = 0.f;
        #pragma unroll
        for (int q = 0; q < 16; ++q) {
            float4 qv = cq[q];
            zo[(size_t)(4 * q + 0) << 12] = qv.x;
            zo[(size_t)(4 * q + 1) << 12] = qv.y;
            zo[(size_t)(4 * q + 2) << 12] = qv.z;
            zo[(size_t)(4 * q + 3) << 12] = qv.w;
            lsum = fmaf(qv.x - zrow[4 * q + 0], qv.x - zrow[4 * q + 0], lsum);
            lsum = fmaf(qv.y - zrow[4 * q + 1], qv.y - zrow[4 * q + 1], lsum);
            lsum = fmaf(qv.z - zrow[4 * q + 2], qv.z - zrow[4 * q + 2], lsum);
            lsum = fmaf(qv.w - zrow[4 * q + 3], qv.w - zrow[4 * q + 3], lsum);
        }

        double ls = (double)lsum;
        for (int off = 32; off > 0; off >>= 1) ls += __shfl_down(ls, off, 64);
        if ((tid & 63) == 0) sP2[tid >> 6] = ls;
    }
    __syncthreads();
    if (tid == 0) part[blockIdx.x] = sP2[0] + sP2[1];
}

__global__ void vq_finalize(const double* __restrict__ part, float* __restrict__ loss_out) {
    __shared__ double s[16];
    const int tid = threadIdx.x;       // 1024 threads, one block
    double v = part[tid];
    for (int off = 32; off > 0; off >>= 1) v += __shfl_down(v, off, 64);
    if ((tid & 63) == 0) s[tid >> 6] = v;
    __syncthreads();
    if (tid == 0) {
        double t = 0.0;
        #pragma unroll
        for (int i = 0; i < 16; ++i) t += s[i];
        // loss = codebook_loss + 0.25*commitment = 1.25 * mean((z_q - z)^2)
        *loss_out = (float)(1.25 * t / (double)ZQ_ELEMS);
    }
}

extern "C" void kernel_launch(void* const* d_in, const int* in_sizes, int n_in,
                              void* d_out, int out_size, void* d_ws, size_t ws_size,
                              hipStream_t stream) {
    const float* z  = (const float*)d_in[0];
    const float* cb = (const float*)d_in[1];
    float* out  = (float*)d_out;
    float* zq   = out;                       // 8388608
    float* loss = out + ZQ_ELEMS;            // 1
    float* idx  = out + ZQ_ELEMS + 1;        // 131072
    char* ws = (char*)d_ws;
    double* part = (double*)ws;              // 1024 doubles
    float* Bsq   = (float*)(ws + WS_BSQ_OFF);
    __bf16* e1   = (__bf16*)(ws + WS_E1_OFF);
    __bf16* e2   = (__bf16*)(ws + WS_E2_OFF);

    vq_prep<<<4, 256, 0, stream>>>(cb, Bsq, e1, e2);
    vq_main<<<NBLK, 256, 0, stream>>>(z, cb, Bsq, e1, e2, zq, idx, part);
    vq_finalize<<<1, 1024, 0, stream>>>(part, loss);
}

// Round 9
// 105.805 us; speedup vs baseline: 3.4382x; 1.8945x over previous
//
#include <hip/hip_runtime.h>

#define CDIM 64
#define KCODES 1024
#define ZQ_ELEMS (32 * 64 * 64 * 64)  // 8388608
#define NROWS 131072
#define FLT_BIG 3.402823466e38f
#define RPB 128                       // rows per block
#define NBLK (NROWS / RPB)            // 1024
#define CSLOTS 48                     // 16 lanes x top-3 per row
#define DELTA 1e-4f                   // screening slack (capture bound ~2.8e-5)

// ws layout: [0,8KB) part | [16KB,20KB) Bsq | [32KB,+128KB) e1 | then e2
#define WS_BSQ_OFF 16384
#define WS_E1_OFF  32768
#define WS_E2_OFF  (32768 + 131072)

typedef __bf16 bf16x8 __attribute__((ext_vector_type(8)));
typedef float  f32x4  __attribute__((ext_vector_type(4)));

// numpy-exact pairwise sum of squares (8 accumulators, numpy pairwise order)
__device__ __forceinline__ float pairwise_sq64(const float* v) {
    float r[8];
    #pragma unroll
    for (int j = 0; j < 8; ++j) r[j] = __fmul_rn(v[j], v[j]);
    #pragma unroll
    for (int m = 1; m < 8; ++m) {
        #pragma unroll
        for (int j = 0; j < 8; ++j)
            r[j] = __fadd_rn(r[j], __fmul_rn(v[8 * m + j], v[8 * m + j]));
    }
    return __fadd_rn(__fadd_rn(__fadd_rn(r[0], r[1]), __fadd_rn(r[2], r[3])),
                     __fadd_rn(__fadd_rn(r[4], r[5]), __fadd_rn(r[6], r[7])));
}

// ---------------- prep: exact code norms + bf16-split codebook, B-fragment layout ----
// B-frag (16x16x32): lane l supplies code tile*16+(l&15), k-elems 8*(l>>4)+i (+32*kstep).
__global__ __launch_bounds__(256) void vq_prep(const float* __restrict__ cb,
                                               float* __restrict__ Bsq,
                                               __bf16* __restrict__ e1,
                                               __bf16* __restrict__ e2) {
    const int k = blockIdx.x * 256 + threadIdx.x;   // 4 blocks -> 1024 codes
    const float* __restrict__ ck = cb + k * CDIM;
    float v[CDIM];
    #pragma unroll
    for (int q = 0; q < 16; ++q) {
        float4 t = ((const float4*)ck)[q];
        v[4 * q + 0] = t.x; v[4 * q + 1] = t.y; v[4 * q + 2] = t.z; v[4 * q + 3] = t.w;
    }
    Bsq[k] = pairwise_sq64(v);

    __bf16 h[CDIM], l[CDIM];
    #pragma unroll
    for (int c = 0; c < CDIM; ++c) {
        h[c] = (__bf16)v[c];
        l[c] = (__bf16)(v[c] - (float)h[c]);
    }
    const int t = k >> 4, kin = k & 15;
    bf16x8* F1 = (bf16x8*)e1;
    bf16x8* F2 = (bf16x8*)e2;
    #pragma unroll
    for (int ks = 0; ks < 2; ++ks) {
        #pragma unroll
        for (int g = 0; g < 4; ++g) {
            bf16x8 a, b;
            #pragma unroll
            for (int i = 0; i < 8; ++i) {
                a[i] = h[ks * 32 + 8 * g + i];
                b[i] = l[ks * 32 + 8 * g + i];
            }
            const int off = (t * 2 + ks) * 64 + ((g << 4) | kin);
            F1[off] = a;
            F2[off] = b;
        }
    }
}

// Build one z fragment-half (8 elems at c = 32*Q + 8*g + i) for row ROW, hi+lo bf16.
#define BUILDZ(H, L, ROW, Q)                                            \
    {                                                                   \
        bf16x8 hh, ll;                                                  \
        _Pragma("unroll")                                               \
        for (int i = 0; i < 8; ++i) {                                   \
            float fv = zb[((size_t)(32 * (Q) + 8 * g + i) << 12) + (ROW)]; \
            __bf16 hv = (__bf16)fv;                                     \
            hh[i] = hv;                                                 \
            ll[i] = (__bf16)(fv - (float)hv);                           \
        }                                                               \
        H = hh; L = ll;                                                 \
    }

// ---------------- main: MFMA screen (branchless packed-key top-3) + exact rescue ----
__global__ __launch_bounds__(256, 3) void vq_main(const float* __restrict__ z,
                                                  const float* __restrict__ cb,
                                                  const float* __restrict__ Bsq,
                                                  const __bf16* __restrict__ e1,
                                                  const __bf16* __restrict__ e2,
                                                  float* __restrict__ zq_out,
                                                  float* __restrict__ idx_out,
                                                  double* __restrict__ part) {
    __shared__ float  sB[KCODES];           // 4 KB exact code norms
    __shared__ float  sKey[RPB * CSLOTS];   // 24.6 KB packed candidate keys
    __shared__ double sP2[2];

    const int tid = threadIdx.x;
    const int n0 = blockIdx.x * RPB;
    const int b = n0 >> 12;
    const int hw0 = n0 & 4095;
    const float* __restrict__ zb = z + ((size_t)b << 18) + hw0;

    for (int k = tid; k < KCODES; k += 256) sB[k] = Bsq[k];

    const int lane = tid & 63, w = tid >> 6;
    const int g = lane >> 4, li = lane & 15;
    const int rowA = 32 * w + li;
    const int rowB = rowA + 16;

    // one-time z fragment build (global, strided; never touched again in k-loop)
    bf16x8 zh00, zh01, zh10, zh11, zl00, zl01, zl10, zl11;
    BUILDZ(zh00, zl00, rowA, 0)
    BUILDZ(zh01, zl01, rowA, 1)
    BUILDZ(zh10, zl10, rowB, 0)
    BUILDZ(zh11, zl11, rowB, 1)

    __syncthreads();   // sB ready

    // packed-key top-3 per (set, j): value in high 22 bits, code in low 10
    float K0[2][4], K1[2][4], K2[2][4];
    #pragma unroll
    for (int s = 0; s < 2; ++s)
        #pragma unroll
        for (int j = 0; j < 4; ++j) { K0[s][j] = FLT_BIG; K1[s][j] = FLT_BIG; K2[s][j] = FLT_BIG; }

    const bf16x8* __restrict__ F1 = (const bf16x8*)e1;
    const bf16x8* __restrict__ F2 = (const bf16x8*)e2;
    const f32x4 zero = {0.f, 0.f, 0.f, 0.f};

    for (int t = 0; t < 64; ++t) {
        const bf16x8 e1a = F1[(2 * t) * 64 + lane];
        const bf16x8 e1b = F1[(2 * t + 1) * 64 + lane];
        const bf16x8 e2a = F2[(2 * t) * 64 + lane];
        const bf16x8 e2b = F2[(2 * t + 1) * 64 + lane];
        const float Bval = sB[(t << 4) | li];
        const int tbli = (t << 4) | li;

        f32x4 aA0 = __builtin_amdgcn_mfma_f32_16x16x32_bf16(zh00, e1a, zero, 0, 0, 0);
        aA0       = __builtin_amdgcn_mfma_f32_16x16x32_bf16(zh01, e1b, aA0, 0, 0, 0);
        f32x4 aB0 = __builtin_amdgcn_mfma_f32_16x16x32_bf16(zh00, e2a, zero, 0, 0, 0);
        aB0       = __builtin_amdgcn_mfma_f32_16x16x32_bf16(zh01, e2b, aB0, 0, 0, 0);
        aB0       = __builtin_amdgcn_mfma_f32_16x16x32_bf16(zl00, e1a, aB0, 0, 0, 0);
        aB0       = __builtin_amdgcn_mfma_f32_16x16x32_bf16(zl01, e1b, aB0, 0, 0, 0);
        f32x4 aA1 = __builtin_amdgcn_mfma_f32_16x16x32_bf16(zh10, e1a, zero, 0, 0, 0);
        aA1       = __builtin_amdgcn_mfma_f32_16x16x32_bf16(zh11, e1b, aA1, 0, 0, 0);
        f32x4 aB1 = __builtin_amdgcn_mfma_f32_16x16x32_bf16(zh10, e2a, zero, 0, 0, 0);
        aB1       = __builtin_amdgcn_mfma_f32_16x16x32_bf16(zh11, e2b, aB1, 0, 0, 0);
        aB1       = __builtin_amdgcn_mfma_f32_16x16x32_bf16(zl10, e1a, aB1, 0, 0, 0);
        aB1       = __builtin_amdgcn_mfma_f32_16x16x32_bf16(zl11, e1b, aB1, 0, 0, 0);

        #pragma unroll
        for (int s = 0; s < 2; ++s) {
            #pragma unroll
            for (int j = 0; j < 4; ++j) {
                const float acc = (s == 0) ? (aA0[j] + aB0[j]) : (aA1[j] + aB1[j]);
                const float v = __fmaf_rn(-2.f, acc, Bval);
                const float kk = __int_as_float((__float_as_int(v) & 0xFFFFFC00) | tbli);
                // branchless sorted-3 insert (min/med/max network)
                const float t0 = K0[s][j], t1 = K1[s][j], t2 = K2[s][j];
                const float mn = fminf(t0, kk), mx = fmaxf(t0, kk);
                K2[s][j] = fminf(t2, fmaxf(t1, kk));
                K1[s][j] = fmaxf(mn, fminf(mx, t1));
                K0[s][j] = mn;
            }
        }
    }

    // write per-lane top-3 keys (D layout: col=lane&15, row=4*(lane>>4)+j)
    #pragma unroll
    for (int s = 0; s < 2; ++s) {
        #pragma unroll
        for (int j = 0; j < 4; ++j) {
            const int row = 32 * w + 16 * s + 4 * g + j;
            const int base = row * CSLOTS + li * 3;
            sKey[base + 0] = K0[s][j];
            sKey[base + 1] = K1[s][j];
            sKey[base + 2] = K2[s][j];
        }
    }
    __syncthreads();

    // ---- exact numpy-semantics rescue, one thread per row ----
    if (tid < RPB) {
        const int r = tid;
        const int n = n0 + r;

        float gmin = FLT_BIG;
        #pragma unroll
        for (int s2 = 0; s2 < CSLOTS; ++s2) gmin = fminf(gmin, sKey[r * CSLOTS + s2]);
        const float thr = gmin + DELTA;

        float zrow[CDIM];
        const float* __restrict__ zp = zb + r;
        #pragma unroll
        for (int c = 0; c < CDIM; ++c) zrow[c] = zp[(size_t)c << 12];  // coalesced
        const float A = pairwise_sq64(zrow);

        float bd = FLT_BIG;
        int bk = 1 << 30;
        for (int s2 = 0; s2 < CSLOTS; ++s2) {
            const float kv = sKey[r * CSLOTS + s2];
            if (kv <= thr) {
                const int k = __float_as_int(kv) & 0x3FF;
                const float4* __restrict__ ek = (const float4*)(cb + (size_t)k * CDIM);
                float m = 0.f;
                #pragma unroll
                for (int q = 0; q < 16; ++q) {      // BLAS order: sequential in c
                    float4 e = ek[q];
                    m = __fmaf_rn(zrow[4 * q + 0], e.x, m);
                    m = __fmaf_rn(zrow[4 * q + 1], e.y, m);
                    m = __fmaf_rn(zrow[4 * q + 2], e.z, m);
                    m = __fmaf_rn(zrow[4 * q + 3], e.w, m);
                }
                const float d = __fsub_rn(__fadd_rn(A, sB[k]), __fadd_rn(m, m));
                if (d < bd || (d == bd && k < bk)) { bd = d; bk = k; }
            }
        }

        idx_out[n] = (float)bk;

        const float4* __restrict__ cq = (const float4*)(cb + (size_t)bk * CDIM);
        float* __restrict__ zo = zq_out + ((size_t)b << 18) + hw0 + r;
        float lsum = 0.f;
        #pragma unroll
        for (int q = 0; q < 16; ++q) {
            float4 qv = cq[q];
            zo[(size_t)(4 * q + 0) << 12] = qv.x;
            zo[(size_t)(4 * q + 1) << 12] = qv.y;
            zo[(size_t)(4 * q + 2) << 12] = qv.z;
            zo[(size_t)(4 * q + 3) << 12] = qv.w;
            lsum = fmaf(qv.x - zrow[4 * q + 0], qv.x - zrow[4 * q + 0], lsum);
            lsum = fmaf(qv.y - zrow[4 * q + 1], qv.y - zrow[4 * q + 1], lsum);
            lsum = fmaf(qv.z - zrow[4 * q + 2], qv.z - zrow[4 * q + 2], lsum);
            lsum = fmaf(qv.w - zrow[4 * q + 3], qv.w - zrow[4 * q + 3], lsum);
        }

        double ls = (double)lsum;
        for (int off = 32; off > 0; off >>= 1) ls += __shfl_down(ls, off, 64);
        if ((tid & 63) == 0) sP2[tid >> 6] = ls;
    }
    __syncthreads();
    if (tid == 0) part[blockIdx.x] = sP2[0] + sP2[1];
}

__global__ void vq_finalize(const double* __restrict__ part, float* __restrict__ loss_out) {
    __shared__ double s[16];
    const int tid = threadIdx.x;       // 1024 threads, one block
    double v = part[tid];
    for (int off = 32; off > 0; off >>= 1) v += __shfl_down(v, off, 64);
    if ((tid & 63) == 0) s[tid >> 6] = v;
    __syncthreads();
    if (tid == 0) {
        double t = 0.0;
        #pragma unroll
        for (int i = 0; i < 16; ++i) t += s[i];
        // loss = codebook_loss + 0.25*commitment = 1.25 * mean((z_q - z)^2)
        *loss_out = (float)(1.25 * t / (double)ZQ_ELEMS);
    }
}

extern "C" void kernel_launch(void* const* d_in, const int* in_sizes, int n_in,
                              void* d_out, int out_size, void* d_ws, size_t ws_size,
                              hipStream_t stream) {
    const float* z  = (const float*)d_in[0];
    const float* cb = (const float*)d_in[1];
    float* out  = (float*)d_out;
    float* zq   = out;                       // 8388608
    float* loss = out + ZQ_ELEMS;            // 1
    float* idx  = out + ZQ_ELEMS + 1;        // 131072
    char* ws = (char*)d_ws;
    double* part = (double*)ws;              // 1024 doubles
    float* Bsq   = (float*)(ws + WS_BSQ_OFF);
    __bf16* e1   = (__bf16*)(ws + WS_E1_OFF);
    __bf16* e2   = (__bf16*)(ws + WS_E2_OFF);

    vq_prep<<<4, 256, 0, stream>>>(cb, Bsq, e1, e2);
    vq_main<<<NBLK, 256, 0, stream>>>(z, cb, Bsq, e1, e2, zq, idx, part);
    vq_finalize<<<1, 1024, 0, stream>>>(part, loss);
}

// Round 10
// 98.291 us; speedup vs baseline: 3.7010x; 1.0765x over previous
//
#include <hip/hip_runtime.h>

#define CDIM 64
#define KCODES 1024
#define ZQ_ELEMS (32 * 64 * 64 * 64)  // 8388608
#define NROWS 131072
#define FLT_BIG 3.402823466e38f
#define RPB 128                       // rows per block
#define NBLK (NROWS / RPB)            // 1024
#define CSTRIDE 49                    // sKey row stride (floats); 48 slots used
#define DELTA 1e-4f                   // screening slack (capture bound ~4.8e-5)

// ws layout: [0,8KB) part | [16KB,20KB) Bsq | [32KB,+128KB) e1 | then e2
#define WS_BSQ_OFF 16384
#define WS_E1_OFF  32768
#define WS_E2_OFF  (32768 + 131072)

typedef __bf16 bf16x8 __attribute__((ext_vector_type(8)));
typedef float  f32x4  __attribute__((ext_vector_type(4)));

// numpy-exact pairwise sum of squares (8 accumulators, numpy pairwise order)
__device__ __forceinline__ float pairwise_sq64(const float* v) {
    float r[8];
    #pragma unroll
    for (int j = 0; j < 8; ++j) r[j] = __fmul_rn(v[j], v[j]);
    #pragma unroll
    for (int m = 1; m < 8; ++m) {
        #pragma unroll
        for (int j = 0; j < 8; ++j)
            r[j] = __fadd_rn(r[j], __fmul_rn(v[8 * m + j], v[8 * m + j]));
    }
    return __fadd_rn(__fadd_rn(__fadd_rn(r[0], r[1]), __fadd_rn(r[2], r[3])),
                     __fadd_rn(__fadd_rn(r[4], r[5]), __fadd_rn(r[6], r[7])));
}

// ---------------- prep: exact code norms + bf16-split codebook, B-fragment layout ----
__global__ __launch_bounds__(256) void vq_prep(const float* __restrict__ cb,
                                               float* __restrict__ Bsq,
                                               __bf16* __restrict__ e1,
                                               __bf16* __restrict__ e2) {
    const int k = blockIdx.x * 256 + threadIdx.x;   // 4 blocks -> 1024 codes
    const float* __restrict__ ck = cb + k * CDIM;
    float v[CDIM];
    #pragma unroll
    for (int q = 0; q < 16; ++q) {
        float4 t = ((const float4*)ck)[q];
        v[4 * q + 0] = t.x; v[4 * q + 1] = t.y; v[4 * q + 2] = t.z; v[4 * q + 3] = t.w;
    }
    Bsq[k] = pairwise_sq64(v);

    __bf16 h[CDIM], l[CDIM];
    #pragma unroll
    for (int c = 0; c < CDIM; ++c) {
        h[c] = (__bf16)v[c];
        l[c] = (__bf16)(v[c] - (float)h[c]);
    }
    const int t = k >> 4, kin = k & 15;
    bf16x8* F1 = (bf16x8*)e1;
    bf16x8* F2 = (bf16x8*)e2;
    #pragma unroll
    for (int ks = 0; ks < 2; ++ks) {
        #pragma unroll
        for (int g = 0; g < 4; ++g) {
            bf16x8 a, b;
            #pragma unroll
            for (int i = 0; i < 8; ++i) {
                a[i] = h[ks * 32 + 8 * g + i];
                b[i] = l[ks * 32 + 8 * g + i];
            }
            const int off = (t * 2 + ks) * 64 + ((g << 4) | kin);
            F1[off] = a;
            F2[off] = b;
        }
    }
}

// branchless sorted-3 insert: 1 min + 2 med3
#define INS(s, j, accv) \
    { \
        const float v = __fmaf_rn(-2.f, (accv), Bval); \
        const float kk = __int_as_float((__float_as_int(v) & 0xFFFFFC00) | tbli); \
        const float o0 = K0[s][j], o1 = K1[s][j], o2 = K2[s][j]; \
        K0[s][j] = fminf(o0, kk); \
        K1[s][j] = __builtin_amdgcn_fmed3f(o0, o1, kk); \
        K2[s][j] = __builtin_amdgcn_fmed3f(o1, o2, kk); \
    }

// ---------------- main: MFMA screen (LDS-staged fragments) + exact rescue ----
__global__ __launch_bounds__(256, 4) void vq_main(const float* __restrict__ z,
                                                  const float* __restrict__ cb,
                                                  const float* __restrict__ Bsq,
                                                  const __bf16* __restrict__ e1,
                                                  const __bf16* __restrict__ e2,
                                                  float* __restrict__ zq_out,
                                                  float* __restrict__ idx_out,
                                                  double* __restrict__ part) {
    // union: [phase 0/1] 32 frag-planes x 65 slots x 16B = 33280 B
    //        [phase 2]   sKey: 128 rows x 49 floats   = 25088 B
    __shared__ __align__(16) unsigned char sU[32 * 65 * 16];
    __shared__ float  sB[KCODES];
    __shared__ double sP2[2];

    const int tid = threadIdx.x;
    const int n0 = blockIdx.x * RPB;
    const int b = n0 >> 12;
    const int hw0 = n0 & 4095;
    const float* __restrict__ zb = z + ((size_t)b << 18) + hw0;

    for (int k = tid; k < KCODES; k += 256) sB[k] = Bsq[k];

    // ---- phase 0: cooperative z staging into bf16 hi/lo fragment planes ----
    // plane(w,H,s,Q) = w*8 + H*4 + s*2 + Q ; slot = g*16+li ; 65 slots/plane
    {
        bf16x8* __restrict__ zfw = (bf16x8*)sU;
        const int r = tid & 127;             // row
        const int h = tid >> 7;              // Q half
        const int w = r >> 5, s = (r >> 4) & 1, li = r & 15;
        #pragma unroll
        for (int g = 0; g < 4; ++g) {
            bf16x8 hi, lo;
            #pragma unroll
            for (int i = 0; i < 8; ++i) {
                const float fv = zb[((size_t)(32 * h + 8 * g + i) << 12) + r];
                const __bf16 hv = (__bf16)fv;
                hi[i] = hv;
                lo[i] = (__bf16)(fv - (float)hv);
            }
            const int slot = (g << 4) | li;
            zfw[(w * 8 + s * 2 + h) * 65 + slot] = hi;         // H=0
            zfw[(w * 8 + 4 + s * 2 + h) * 65 + slot] = lo;     // H=1
        }
    }
    __syncthreads();

    // ---- phase 1: MFMA screen; wave w owns rows [32w,32w+32) x all 1024 codes ----
    const int lane = tid & 63, w = tid >> 6;
    const int g = lane >> 4, li = lane & 15;

    const bf16x8* __restrict__ zf = (const bf16x8*)sU;
    const bf16x8 zh00 = zf[(w * 8 + 0) * 65 + lane];
    const bf16x8 zh01 = zf[(w * 8 + 1) * 65 + lane];
    const bf16x8 zh10 = zf[(w * 8 + 2) * 65 + lane];
    const bf16x8 zh11 = zf[(w * 8 + 3) * 65 + lane];
    const bf16x8 zl00 = zf[(w * 8 + 4) * 65 + lane];
    const bf16x8 zl01 = zf[(w * 8 + 5) * 65 + lane];
    const bf16x8 zl10 = zf[(w * 8 + 6) * 65 + lane];
    const bf16x8 zl11 = zf[(w * 8 + 7) * 65 + lane];

    float K0[2][4], K1[2][4], K2[2][4];
    #pragma unroll
    for (int s = 0; s < 2; ++s)
        #pragma unroll
        for (int j = 0; j < 4; ++j) { K0[s][j] = FLT_BIG; K1[s][j] = FLT_BIG; K2[s][j] = FLT_BIG; }

    const bf16x8* __restrict__ pe1 = (const bf16x8*)e1 + lane;
    const bf16x8* __restrict__ pe2 = (const bf16x8*)e2 + lane;
    const f32x4 zero = {0.f, 0.f, 0.f, 0.f};
    int tbli = li;

    for (int t = 0; t < 64; ++t) {
        const bf16x8 e1a = pe1[0];
        const bf16x8 e1b = pe1[64];
        const bf16x8 e2a = pe2[0];
        const bf16x8 e2b = pe2[64];
        const float Bval = sB[tbli];

        f32x4 aA0 = __builtin_amdgcn_mfma_f32_16x16x32_bf16(zh00, e1a, zero, 0, 0, 0);
        aA0       = __builtin_amdgcn_mfma_f32_16x16x32_bf16(zh01, e1b, aA0, 0, 0, 0);
        f32x4 aB0 = __builtin_amdgcn_mfma_f32_16x16x32_bf16(zh00, e2a, zero, 0, 0, 0);
        aB0       = __builtin_amdgcn_mfma_f32_16x16x32_bf16(zh01, e2b, aB0, 0, 0, 0);
        aB0       = __builtin_amdgcn_mfma_f32_16x16x32_bf16(zl00, e1a, aB0, 0, 0, 0);
        aB0       = __builtin_amdgcn_mfma_f32_16x16x32_bf16(zl01, e1b, aB0, 0, 0, 0);
        f32x4 aA1 = __builtin_amdgcn_mfma_f32_16x16x32_bf16(zh10, e1a, zero, 0, 0, 0);
        aA1       = __builtin_amdgcn_mfma_f32_16x16x32_bf16(zh11, e1b, aA1, 0, 0, 0);
        f32x4 aB1 = __builtin_amdgcn_mfma_f32_16x16x32_bf16(zh10, e2a, zero, 0, 0, 0);
        aB1       = __builtin_amdgcn_mfma_f32_16x16x32_bf16(zh11, e2b, aB1, 0, 0, 0);
        aB1       = __builtin_amdgcn_mfma_f32_16x16x32_bf16(zl10, e1a, aB1, 0, 0, 0);
        aB1       = __builtin_amdgcn_mfma_f32_16x16x32_bf16(zl11, e1b, aB1, 0, 0, 0);

        #pragma unroll
        for (int j = 0; j < 4; ++j) INS(0, j, aA0[j] + aB0[j])
        #pragma unroll
        for (int j = 0; j < 4; ++j) INS(1, j, aA1[j] + aB1[j])

        pe1 += 128;
        pe2 += 128;
        tbli += 16;
    }

    __syncthreads();   // frag planes dead; reuse sU as sKey

    float* __restrict__ sKey = (float*)sU;
    #pragma unroll
    for (int s = 0; s < 2; ++s) {
        #pragma unroll
        for (int j = 0; j < 4; ++j) {
            const int row = 32 * w + 16 * s + 4 * g + j;
            const int base = row * CSTRIDE + li * 3;
            sKey[base + 0] = K0[s][j];
            sKey[base + 1] = K1[s][j];
            sKey[base + 2] = K2[s][j];
        }
    }
    __syncthreads();

    // ---- phase 2: exact numpy-semantics rescue, one thread per row ----
    if (tid < RPB) {
        const int r = tid;
        const int n = n0 + r;

        float gmin = FLT_BIG;
        #pragma unroll
        for (int s2 = 0; s2 < 48; ++s2) gmin = fminf(gmin, sKey[r * CSTRIDE + s2]);
        const float thr = gmin + DELTA;

        float zrow[CDIM];
        const float* __restrict__ zp = zb + r;
        #pragma unroll
        for (int c = 0; c < CDIM; ++c) zrow[c] = zp[(size_t)c << 12];  // coalesced
        const float A = pairwise_sq64(zrow);

        float bd = FLT_BIG;
        int bk = 1 << 30;
        for (int s2 = 0; s2 < 48; ++s2) {
            const float kv = sKey[r * CSTRIDE + s2];
            if (kv <= thr) {
                const int k = __float_as_int(kv) & 0x3FF;
                const float4* __restrict__ ek = (const float4*)(cb + (size_t)k * CDIM);
                float m = 0.f;
                #pragma unroll
                for (int q = 0; q < 16; ++q) {      // BLAS order: sequential in c
                    float4 e = ek[q];
                    m = __fmaf_rn(zrow[4 * q + 0], e.x, m);
                    m = __fmaf_rn(zrow[4 * q + 1], e.y, m);
                    m = __fmaf_rn(zrow[4 * q + 2], e.z, m);
                    m = __fmaf_rn(zrow[4 * q + 3], e.w, m);
                }
                const float d = __fsub_rn(__fadd_rn(A, sB[k]), __fadd_rn(m, m));
                if (d < bd || (d == bd && k < bk)) { bd = d; bk = k; }
            }
        }

        idx_out[n] = (float)bk;

        const float4* __restrict__ cq = (const float4*)(cb + (size_t)bk * CDIM);
        float* __restrict__ zo = zq_out + ((size_t)b << 18) + hw0 + r;
        float lsum = 0.f;
        #pragma unroll
        for (int q = 0; q < 16; ++q) {
            float4 qv = cq[q];
            zo[(size_t)(4 * q + 0) << 12] = qv.x;
            zo[(size_t)(4 * q + 1) << 12] = qv.y;
            zo[(size_t)(4 * q + 2) << 12] = qv.z;
            zo[(size_t)(4 * q + 3) << 12] = qv.w;
            lsum = fmaf(qv.x - zrow[4 * q + 0], qv.x - zrow[4 * q + 0], lsum);
            lsum = fmaf(qv.y - zrow[4 * q + 1], qv.y - zrow[4 * q + 1], lsum);
            lsum = fmaf(qv.z - zrow[4 * q + 2], qv.z - zrow[4 * q + 2], lsum);
            lsum = fmaf(qv.w - zrow[4 * q + 3], qv.w - zrow[4 * q + 3], lsum);
        }

        double ls = (double)lsum;
        for (int off = 32; off > 0; off >>= 1) ls += __shfl_down(ls, off, 64);
        if ((tid & 63) == 0) sP2[tid >> 6] = ls;
    }
    __syncthreads();
    if (tid == 0) part[blockIdx.x] = sP2[0] + sP2[1];
}

__global__ void vq_finalize(const double* __restrict__ part, float* __restrict__ loss_out) {
    __shared__ double s[16];
    const int tid = threadIdx.x;       // 1024 threads, one block
    double v = part[tid];
    for (int off = 32; off > 0; off >>= 1) v += __shfl_down(v, off, 64);
    if ((tid & 63) == 0) s[tid >> 6] = v;
    __syncthreads();
    if (tid == 0) {
        double t = 0.0;
        #pragma unroll
        for (int i = 0; i < 16; ++i) t += s[i];
        // loss = codebook_loss + 0.25*commitment = 1.25 * mean((z_q - z)^2)
        *loss_out = (float)(1.25 * t / (double)ZQ_ELEMS);
    }
}

extern "C" void kernel_launch(void* const* d_in, const int* in_sizes, int n_in,
                              void* d_out, int out_size, void* d_ws, size_t ws_size,
                              hipStream_t stream) {
    const float* z  = (const float*)d_in[0];
    const float* cb = (const float*)d_in[1];
    float* out  = (float*)d_out;
    float* zq   = out;                       // 8388608
    float* loss = out + ZQ_ELEMS;            // 1
    float* idx  = out + ZQ_ELEMS + 1;        // 131072
    char* ws = (char*)d_ws;
    double* part = (double*)ws;              // 1024 doubles
    float* Bsq   = (float*)(ws + WS_BSQ_OFF);
    __bf16* e1   = (__bf16*)(ws + WS_E1_OFF);
    __bf16* e2   = (__bf16*)(ws + WS_E2_OFF);

    vq_prep<<<4, 256, 0, stream>>>(cb, Bsq, e1, e2);
    vq_main<<<NBLK, 256, 0, stream>>>(z, cb, Bsq, e1, e2, zq, idx, part);
    vq_finalize<<<1, 1024, 0, stream>>>(part, loss);
}